// Round 7
// baseline (210.481 us; speedup 1.0000x reference)
//
#include <hip/hip_runtime.h>
#include <hip/hip_bf16.h>
#include <stdint.h>

// Problem constants (from reference)
#define C_   8
#define EPC_ 4
#define E_   32
#define K_   8
#define S_   256
#define H_   2048
#define M_   2048
#define ML_  8
#define CAP_ 256               // M / C
#define SK_  2048              // S*K
#define NROWS_ (E_ * M_)       // 65536 slot rows (r = e*M + dst)
#define BUF_ELEMS_ ((size_t)E_ * M_ * H_)   // 134217728
#define RPB_ 8                 // rows per fill block (64 KB of buf)

typedef float f32x4 __attribute__((ext_vector_type(4)));

// ---------------------------------------------------------------------------
// Kernel 1: wave-parallel stable rank. One wave per (chip, expert): 256 waves.
// For pick (c,i) with indices[c,i]==e, rank = #earlier matches (ballot+popc).
// Emits inv[e*M + dst] = pick id (c*SK + i) for in-bounds dst, and
// cnt[c*E+e] = total matches. Occupied slots form a dense prefix of each
// (e,chip) 256-slot region (expert_offsets[c,e] = c*CAP, cnt << CAP), so
// consumers only read inv[] inside the prefix -> no init pass needed.
// ---------------------------------------------------------------------------
__global__ __launch_bounds__(64) void rank_kernel(
        const int* __restrict__ indices,
        const int* __restrict__ expert_offsets,
        int* __restrict__ inv,
        int* __restrict__ cnt) {
    const int c    = blockIdx.x >> 5;
    const int e    = blockIdx.x & 31;
    const int lane = threadIdx.x;
    const int* __restrict__ ip = indices + c * SK_;
    const int base = expert_offsets[c * E_ + e];

    int running = 0;
    const unsigned long long below = (lane == 63) ? (~0ULL >> 1)
                                                  : (1ULL << lane) - 1ULL;
    #pragma unroll 4
    for (int ch = 0; ch < SK_ / 64; ++ch) {
        const int i = ch * 64 + lane;
        const bool hit = (ip[i] == e);
        const unsigned long long m = __ballot(hit);
        if (hit) {
            const int dst = base + running + __popcll(m & below);
            if ((unsigned)dst < (unsigned)M_) {
                inv[e * M_ + dst] = c * SK_ + i;
            }
        }
        running += __popcll(m);
    }
    if (lane == 0) cnt[c * E_ + e] = running;
}

// ---------------------------------------------------------------------------
// Kernel 2: destination-ordered fill — the WHOLE output written as one
// sequential stream (the rocclr-fill pattern that sustains 6.7 TB/s).
// Block b covers rows [b*8, b*8+8) = 64 KB of buf, written in address order.
// All 8 rows share one (e, chip): e changes every 2048 rows, c every 256.
// Rows j < nocc copy x[pick row] (scattered PLAIN loads — x is 16.8 MB,
// LLC-resident, ~8x reuse); rows >= nocc write zeros. NT stores on buf keep
// the 512 MiB write stream from evicting x out of the Infinity Cache.
// Threads 0..7 write the 8 meta rows (float-encoded ints; the harness reads
// d_out as one f32 array).
// ---------------------------------------------------------------------------
__global__ __launch_bounds__(256) void fill_dst(
        const float* __restrict__ x,
        const float* __restrict__ w,
        const int* __restrict__ inv,
        const int* __restrict__ cnt,
        float* __restrict__ buf,
        float* __restrict__ meta) {
    const int r0    = blockIdx.x * RPB_;
    const int e     = r0 >> 11;            // r = e*M + dst
    const int dst0  = r0 & (M_ - 1);
    const int c     = dst0 >> 8;           // CAP = 256
    const int slot0 = dst0 & (CAP_ - 1);
    const int t     = threadIdx.x;

    int nocc = cnt[c * E_ + e] - slot0;    // rows j < nocc are occupied
    nocc = (nocc < 0) ? 0 : ((nocc > RPB_) ? RPB_ : nocc);

    // Picks for occupied rows (block-uniform scalar loads).
    int p[RPB_];
    #pragma unroll
    for (int j = 0; j < RPB_; ++j) p[j] = (j < nocc) ? inv[r0 + j] : -1;

    // Prefetch all occupied x rows into registers. Static indices only
    // (full unroll) so A0/A1 stay in registers; block-uniform branches.
    const f32x4 z = {0.f, 0.f, 0.f, 0.f};
    f32x4 A0[RPB_], A1[RPB_];
    #pragma unroll
    for (int j = 0; j < RPB_; ++j) { A0[j] = z; A1[j] = z; }
    #pragma unroll
    for (int j = 0; j < RPB_; ++j) {
        if (j < nocc) {
            const int pp   = p[j];
            const int srow = (pp >> 11) * S_ + ((pp & (SK_ - 1)) >> 3);
            const f32x4* __restrict__ src =
                reinterpret_cast<const f32x4*>(x + (size_t)srow * H_);
            A0[j] = src[t];
            A1[j] = src[t + 256];
        }
    }

    // Sequential store of the full 64 KB span, rows in address order.
    #pragma unroll
    for (int j = 0; j < RPB_; ++j) {
        f32x4* __restrict__ brow =
            reinterpret_cast<f32x4*>(buf + (size_t)(r0 + j) * H_);
        __builtin_nontemporal_store(A0[j], brow + t);
        __builtin_nontemporal_store(A1[j], brow + t + 256);
    }

    // Meta rows (32 B each), threads 0..7.
    if (t < RPB_) {
        f32x4* __restrict__ mrow =
            reinterpret_cast<f32x4*>(meta + (size_t)(r0 + t) * ML_);
        if (t < nocc) {
            const int pp    = p[t];
            const int cc    = pp >> 11;
            const int i     = pp & (SK_ - 1);
            const int token = i >> 3;
            const int topk  = i & (K_ - 1);
            // wbits: f32 -> bf16 (RNE) -> int16 -> sign-extend int32
            const float wv    = w[pp];     // (cc*S+token)*K+topk == pp
            const uint32_t u  = __float_as_uint(wv);
            const uint32_t rb = (u + 0x7FFFu + ((u >> 16) & 1u)) >> 16;
            const int wb      = (int)(short)(unsigned short)rb;
            const f32x4 m0 = {(float)cc, (float)token, (float)topk, (float)e};
            const f32x4 m1 = {(float)wb, 0.f, 0.f, 0.f};
            __builtin_nontemporal_store(m0, mrow);
            __builtin_nontemporal_store(m1, mrow + 1);
        } else {
            const f32x4 m = {-1.f, -1.f, -1.f, -1.f};
            __builtin_nontemporal_store(m, mrow);
            __builtin_nontemporal_store(m, mrow + 1);
        }
    }
}

// ---------------------------------------------------------------------------
extern "C" void kernel_launch(void* const* d_in, const int* in_sizes, int n_in,
                              void* d_out, int out_size, void* d_ws, size_t ws_size,
                              hipStream_t stream) {
    const float* x   = (const float*)d_in[0];   // (C,S,H) f32
    const float* w   = (const float*)d_in[1];   // (C,S,K) f32
    const int* idx   = (const int*)d_in[2];     // (C,S,K) i32
    const int* eo    = (const int*)d_in[3];     // (C,E)   i32

    float* buf  = (float*)d_out;                 // (1,C,EPC,M,H) f32
    float* meta = buf + BUF_ELEMS_;              // (1,C,EPC,M,ML), float-encoded

    int* inv = (int*)d_ws;                       // E*M int32 = 256 KiB
    int* cnt = inv + NROWS_;                     // C*E int32 = 1 KiB

    // 1: stable ranks -> inverse map (row -> pick) + per-(c,e) counts
    rank_kernel<<<C_ * E_, 64, 0, stream>>>(idx, eo, inv, cnt);
    // 2: one sequential write pass over the entire output
    fill_dst<<<NROWS_ / RPB_, 256, 0, stream>>>(x, w, inv, cnt, buf, meta);
}

// Round 8
// 106.515 us; speedup vs baseline: 1.9761x; 1.9761x over previous
//
#include <hip/hip_runtime.h>
#include <hip/hip_bf16.h>
#include <stdint.h>

// Problem constants (from reference)
#define C_   8
#define EPC_ 4
#define E_   32
#define K_   8
#define S_   256
#define H_   2048
#define M_   2048
#define ML_  8
#define CAP_ 256               // M / C
#define SK_  2048              // S*K
#define NROWS_ (E_ * M_)       // 65536 slot rows (r = e*M + dst)
#define BUF_ELEMS_ ((size_t)E_ * M_ * H_)   // 134217728
#define ZROWS_PER_BLOCK_ 8
#define NZERO_   (NROWS_ / ZROWS_PER_BLOCK_) // 8192 zero blocks
#define GSPLIT_  2                           // picks split across 2 blocks
#define KH_      (K_ / GSPLIT_)              // 4 picks per gather block
#define NGATHER_ (C_ * S_ * GSPLIT_)         // 4096 gather blocks

typedef float f32x4 __attribute__((ext_vector_type(4)));

// ---------------------------------------------------------------------------
// Kernel 1: wave-parallel stable rank. One wave per (chip, expert): 256 waves.
// For pick (c,i) with indices[c,i]==e, rank = #earlier matches (ballot+popc).
// Emits dstmap[c*SK+i] = slot row r = e*M + base + rank (or -1 if OOB drop),
// and cnt[c*E+e] = total matches. Every pick is written exactly once (expert
// ids always in [0,E)), so dstmap needs no init pass.
// ---------------------------------------------------------------------------
__global__ __launch_bounds__(64) void rank_kernel(
        const int* __restrict__ indices,
        const int* __restrict__ expert_offsets,
        int* __restrict__ dstmap,
        int* __restrict__ cnt) {
    const int c    = blockIdx.x >> 5;
    const int e    = blockIdx.x & 31;
    const int lane = threadIdx.x;
    const int* __restrict__ ip = indices + c * SK_;
    const int base = expert_offsets[c * E_ + e];

    int running = 0;
    const unsigned long long below = (lane == 63) ? (~0ULL >> 1)
                                                  : (1ULL << lane) - 1ULL;
    #pragma unroll 4
    for (int ch = 0; ch < SK_ / 64; ++ch) {
        const int i = ch * 64 + lane;
        const bool hit = (ip[i] == e);
        const unsigned long long m = __ballot(hit);
        if (hit) {
            const int dst = base + running + __popcll(m & below);
            dstmap[c * SK_ + i] =
                ((unsigned)dst < (unsigned)M_) ? (e * M_ + dst) : -1;
        }
        running += __popcll(m);
    }
    if (lane == 0) cnt[c * E_ + e] = running;
}

// ---------------------------------------------------------------------------
// Kernel 2 (fused, ZERO-FIRST): one dispatch, two block roles.
//  - blocks [0, NZERO): zero role, 8 consecutive slot rows (64 KB) each.
//    Occupied slots are a dense prefix of each (e,chip) 256-slot region
//    (expert_offsets[c,e] = c*CAP), so one cnt load decides all 8 rows.
//  - blocks [NZERO, NZERO+NGATHER): gather role, TWO blocks per (chip,token),
//    each handling 4 of the K=8 picks (R6->R8 isolated change: doubles tail
//    parallelism, halves per-block serial store depth; x re-read 2x = +17 MB,
//    noise). Reads the x row ONCE per block (NT loads — no reuse), streams it
//    to its 4 destination rows; threads 0..3 write the 4 meta rows.
// Zero-first ordering keeps the 403 MB sequential zero stream pure; gather
// blocks run in the dispatch tail (R4 showed sustained mixing regresses;
// R7 showed scattered-read-per-store-burst is far worse).
// Meta values are FLOAT-encoded ints (harness reads d_out as one f32 array).
// ---------------------------------------------------------------------------
__global__ __launch_bounds__(256) void fill_all(
        const float* __restrict__ x,
        const float* __restrict__ w,
        const int* __restrict__ dstmap,
        const int* __restrict__ cnt,
        float* __restrict__ buf,
        float* __restrict__ meta) {
    const int t = threadIdx.x;

    if (blockIdx.x < NZERO_) {
        // ----- zero role -----
        const int r0    = blockIdx.x * ZROWS_PER_BLOCK_;
        const int e     = r0 >> 11;
        const int dst0  = r0 & (M_ - 1);
        const int c     = dst0 >> 8;
        const int slot0 = dst0 & (CAP_ - 1);

        int nocc = cnt[c * E_ + e] - slot0;      // rows j < nocc are occupied
        if (nocc >= ZROWS_PER_BLOCK_) return;    // whole block occupied
        if (nocc < 0) nocc = 0;

        const f32x4 z = {0.f, 0.f, 0.f, 0.f};
        for (int j = nocc; j < ZROWS_PER_BLOCK_; ++j) {
            f32x4* __restrict__ brow =
                reinterpret_cast<f32x4*>(buf + (size_t)(r0 + j) * H_);
            brow[t]       = z;
            brow[t + 256] = z;
        }
        if (t >= nocc && t < ZROWS_PER_BLOCK_) {
            f32x4* __restrict__ mrow =
                reinterpret_cast<f32x4*>(meta + (size_t)(r0 + t) * ML_);
            const f32x4 m = {-1.f, -1.f, -1.f, -1.f};
            mrow[0] = m;
            mrow[1] = m;
        }
    } else {
        // ----- gather role -----
        const int g     = blockIdx.x - NZERO_;   // 2 blocks per (c,token)
        const int b     = g >> 1;                // c*S + token
        const int half  = g & 1;                 // which 4 picks
        const int c     = b >> 8;
        const int token = b & (S_ - 1);

        const f32x4* __restrict__ src =
            reinterpret_cast<const f32x4*>(x + (size_t)b * H_);
        const f32x4 a0 = __builtin_nontemporal_load(src + t);
        const f32x4 a1 = __builtin_nontemporal_load(src + t + 256);

        const int* __restrict__ dm =
            dstmap + c * SK_ + token * K_ + half * KH_;
        int d[KH_];
        #pragma unroll
        for (int k = 0; k < KH_; ++k) d[k] = dm[k];   // uniform across block

        #pragma unroll
        for (int k = 0; k < KH_; ++k) {
            if (d[k] >= 0) {
                f32x4* __restrict__ brow =
                    reinterpret_cast<f32x4*>(buf + (size_t)d[k] * H_);
                __builtin_nontemporal_store(a0, brow + t);
                __builtin_nontemporal_store(a1, brow + t + 256);
            }
        }

        if (t < KH_) {
            const int k  = t;
            const int dd = d[k];
            if (dd >= 0) {
                const int e = dd >> 11;              // dd = e*M + dst
                // wbits: f32 -> bf16 (RNE) -> int16 -> sign-extend int32
                const float wv    = w[(b * K_) + half * KH_ + k];
                const uint32_t u  = __float_as_uint(wv);
                const uint32_t rb = (u + 0x7FFFu + ((u >> 16) & 1u)) >> 16;
                const int wb      = (int)(short)(unsigned short)rb;
                f32x4* __restrict__ mrow =
                    reinterpret_cast<f32x4*>(meta + (size_t)dd * ML_);
                const f32x4 m0 = {(float)c, (float)token,
                                  (float)(half * KH_ + k), (float)e};
                const f32x4 m1 = {(float)wb, 0.f, 0.f, 0.f};
                __builtin_nontemporal_store(m0, mrow);
                __builtin_nontemporal_store(m1, mrow + 1);
            }
        }
    }
}

// ---------------------------------------------------------------------------
extern "C" void kernel_launch(void* const* d_in, const int* in_sizes, int n_in,
                              void* d_out, int out_size, void* d_ws, size_t ws_size,
                              hipStream_t stream) {
    const float* x   = (const float*)d_in[0];   // (C,S,H) f32
    const float* w   = (const float*)d_in[1];   // (C,S,K) f32
    const int* idx   = (const int*)d_in[2];     // (C,S,K) i32
    const int* eo    = (const int*)d_in[3];     // (C,E)   i32

    float* buf  = (float*)d_out;                 // (1,C,EPC,M,H) f32
    float* meta = buf + BUF_ELEMS_;              // (1,C,EPC,M,ML), float-encoded

    int* dstmap = (int*)d_ws;                    // C*SK int32 = 64 KiB
    int* cnt    = dstmap + C_ * SK_;             // C*E int32  = 1 KiB

    // 1: stable ranks -> per-pick destination rows + per-(c,e) counts
    rank_kernel<<<C_ * E_, 64, 0, stream>>>(idx, eo, dstmap, cnt);
    // 2: fused fill, zero blocks first, split gather blocks trail
    fill_all<<<NZERO_ + NGATHER_, 256, 0, stream>>>(x, w, dstmap, cnt, buf, meta);
}